// Round 6
// baseline (81.098 us; speedup 1.0000x reference)
//
#include <hip/hip_runtime.h>

#define EMB 128
#define BM 128
#define THREADS 512

typedef __attribute__((ext_vector_type(8))) short bf16x8;   // 8 bf16 (4 VGPRs)
typedef __attribute__((ext_vector_type(4))) float f32x4;
typedef unsigned short u16;

__device__ __forceinline__ u16 f2bf(float f) {
    unsigned u = __builtin_bit_cast(unsigned, f);
    u += 0x7fffu + ((u >> 16) & 1u);           // round-to-nearest-even
    return (u16)(u >> 16);
}

// ---- merged pre-kernel ----
// blocks [0,500): Rp[j][n] = sum_k rel[j][k] * Dr[k][n]   (2 rows j per block)
// blocks [500,564): frag-major bf16 image of De:
//   Bimg[((kk*8+ci)*64 + lane)*8 + e] = bf16( De[kk*32+(lane>>4)*8+e][ci*16+(lane&15)] )
__global__ void setup_kernel(const float* __restrict__ rel,
                             const float* __restrict__ Dr,
                             const float* __restrict__ De,
                             float* __restrict__ Rp,
                             u16* __restrict__ Bimg, int nrel) {
    const int blk = blockIdx.x;
    if (blk < 500) {
        const int n = threadIdx.x & 127;
        const int j = blk * 2 + (threadIdx.x >> 7);
        if (j >= nrel) return;
        float a = 0.f;
        for (int k = 0; k < EMB; ++k)
            a = fmaf(rel[(size_t)j * EMB + k], Dr[(size_t)k * EMB + n], a);
        Rp[(size_t)j * EMB + n] = a;
    } else {
        const int idx  = (blk - 500) * 256 + threadIdx.x;   // 0..16383
        const int e    = idx & 7;
        const int lane = (idx >> 3) & 63;
        const int frag = idx >> 9;
        const int ci = frag & 7, kk = frag >> 3;
        const int k = kk * 32 + (lane >> 4) * 8 + e;
        const int n = ci * 16 + (lane & 15);
        Bimg[idx] = f2bf(De[(size_t)k * EMB + n]);
    }
}

// ---- main kernel: B in LDS (32KB only -> 4 blocks/CU = 32 waves/CU) ----
__global__ __launch_bounds__(THREADS, 8)
void projE_main(const int* __restrict__ triple,
                const float* __restrict__ ent,
                const float* __restrict__ bc,
                const float* __restrict__ Rp,
                const u16* __restrict__ Bimg,
                float* __restrict__ out)
{
    __shared__ u16 Bs[16384];       // 32KB, frag-major De image (conflict-free reads)

    const int tid  = threadIdx.x;
    const int lane = tid & 63;
    const int w    = tid >> 6;      // wave 0..7, owns batch rows w*16..w*16+15
    const int l15  = lane & 15;
    const int l4   = lane >> 4;
    const int bm0  = blockIdx.x * BM;

    // ---- stage De image: 32KB linear copy, global -> LDS direct ----
    {
        const __attribute__((address_space(1))) char* gB =
            (const __attribute__((address_space(1))) char*)Bimg;
        __attribute__((address_space(3))) char* lB =
            (__attribute__((address_space(3))) char*)Bs;
        #pragma unroll
        for (int i = 0; i < 4; ++i) {
            const int off = (i * THREADS + tid) * 16;   // wave-uniform base + lane*16
            __builtin_amdgcn_global_load_lds(
                (const __attribute__((address_space(1))) void*)(gB + off),
                (__attribute__((address_space(3))) void*)(lB + off), 16, 0, 0);
        }
    }

    const int g    = bm0 + w * 16 + l15;      // this lane's batch row
    const int hidx = triple[g * 3 + 0];
    const int ridx = triple[g * 3 + 1];
    const int tidx = triple[g * 3 + 2];

    const float* hp = ent + (size_t)hidx * EMB;
    const float* tp = ent + (size_t)tidx * EMB;

    // ---- h gather, lane-private k-slices (cols kk*32+8*l4 .. +7) ----
    float4 hv[8];
    #pragma unroll
    for (int kk = 0; kk < 4; ++kk) {
        hv[2 * kk]     = *reinterpret_cast<const float4*>(hp + kk * 32 + 8 * l4);
        hv[2 * kk + 1] = *reinterpret_cast<const float4*>(hp + kk * 32 + 8 * l4 + 4);
    }

    // ---- t prefetch (held across MFMA; overlaps it) ----
    float4 tv[8];
    #pragma unroll
    for (int ci = 0; ci < 8; ++ci)
        tv[ci] = *reinterpret_cast<const float4*>(tp + ci * 16 + 4 * l4);

    // ---- convert h to bf16 B-operand fragments (hv dies here) ----
    bf16x8 hf[4];
    #pragma unroll
    for (int kk = 0; kk < 4; ++kk) {
        bf16x8 v;
        v[0] = (short)f2bf(hv[2 * kk].x);
        v[1] = (short)f2bf(hv[2 * kk].y);
        v[2] = (short)f2bf(hv[2 * kk].z);
        v[3] = (short)f2bf(hv[2 * kk].w);
        v[4] = (short)f2bf(hv[2 * kk + 1].x);
        v[5] = (short)f2bf(hv[2 * kk + 1].y);
        v[6] = (short)f2bf(hv[2 * kk + 1].z);
        v[7] = (short)f2bf(hv[2 * kk + 1].w);
        hf[kk] = v;
    }

    __syncthreads();   // the only barrier: B visible to all waves

    // ---- MFMA: C[de_n][batch] = De-frag (A, LDS) x h-frag (B, regs) ----
    // C layout: col = l15 = batch row; row = 4*l4 + reg = de_n within fragment ci
    f32x4 acc[8];
    #pragma unroll
    for (int ci = 0; ci < 8; ++ci) acc[ci] = (f32x4){0.f, 0.f, 0.f, 0.f};

    #pragma unroll
    for (int kk = 0; kk < 4; ++kk) {
        #pragma unroll
        for (int ci = 0; ci < 8; ++ci) {
            const bf16x8 d = *reinterpret_cast<const bf16x8*>(&Bs[((kk * 8 + ci) << 6 | lane) * 8]);
            acc[ci] = __builtin_amdgcn_mfma_f32_16x16x32_bf16(d, hf[kk], acc[ci], 0, 0, 0);
        }
    }

    // ---- epilogue: f = tanh(acc + Rp[ridx] + bc); out = sigmoid(f . t) ----
    const float* rp = Rp + (size_t)ridx * EMB;
    const float* bp = bc + (size_t)g    * EMB;

    float dot = 0.f;
    #pragma unroll
    for (int ci = 0; ci < 8; ++ci) {
        const int col = ci * 16 + 4 * l4;      // 4 consecutive cols per lane
        const float4 r4 = *reinterpret_cast<const float4*>(rp + col);
        const float4 b4 = *reinterpret_cast<const float4*>(bp + col);
        #pragma unroll
        for (int e = 0; e < 4; ++e) {
            const float x  = acc[ci][e] + (&r4.x)[e] + (&b4.x)[e];
            const float e2 = __expf(2.f * x);
            const float fv = 1.f - __fdividef(2.f, e2 + 1.f);   // tanh(x), inf-safe
            dot = fmaf(fv, (&tv[ci].x)[e], dot);
        }
    }
    dot += __shfl_xor(dot, 16);
    dot += __shfl_xor(dot, 32);
    if (lane < 16) out[g] = __fdividef(1.f, 1.f + __expf(-dot));
}

extern "C" void kernel_launch(void* const* d_in, const int* in_sizes, int n_in,
                              void* d_out, int out_size, void* d_ws, size_t ws_size,
                              hipStream_t stream) {
    const int*   triple = (const int*)  d_in[0];
    const float* ent    = (const float*)d_in[1];
    const float* rel    = (const float*)d_in[2];
    const float* De     = (const float*)d_in[3];
    const float* Dr     = (const float*)d_in[4];
    const float* bc     = (const float*)d_in[5];
    float* out = (float*)d_out;

    const int batch = in_sizes[0] / 3;          // 131072
    const int nrel  = in_sizes[2] / EMB;        // 1000

    float* Rp = (float*)d_ws;                           // 512000 B
    u16* Bimg = (u16*)((char*)d_ws + 524288);           // 32 KB

    setup_kernel<<<dim3(564), dim3(256), 0, stream>>>(rel, Dr, De, Rp, Bimg, nrel);
    projE_main<<<dim3(batch / BM), dim3(THREADS), 0, stream>>>(triple, ent, bc, Rp, Bimg, out);
}

// Round 7
// 61.171 us; speedup vs baseline: 1.3258x; 1.3258x over previous
//
#include <hip/hip_runtime.h>

#define EMB 128
#define BM 32
#define THREADS 256

typedef __attribute__((ext_vector_type(8))) short bf16x8;   // 8 bf16 (4 VGPRs)
typedef __attribute__((ext_vector_type(4))) float f32x4;
typedef unsigned short u16;

__device__ __forceinline__ u16 f2bf(float f) {
    unsigned u = __builtin_bit_cast(unsigned, f);
    u += 0x7fffu + ((u >> 16) & 1u);           // round-to-nearest-even
    return (u16)(u >> 16);
}

// ---- merged pre-kernel ----
// blocks [0,500): Rp[j][n] = sum_k rel[j][k] * Dr[k][n]   (2 rows j per block)
// blocks [500,564): frag-major bf16 image of De:
//   Bimg[((kk*8+ci)*64 + lane)*8 + e] = bf16( De[kk*32+(lane>>4)*8+e][ci*16+(lane&15)] )
__global__ void setup_kernel(const float* __restrict__ rel,
                             const float* __restrict__ Dr,
                             const float* __restrict__ De,
                             float* __restrict__ Rp,
                             u16* __restrict__ Bimg, int nrel) {
    const int blk = blockIdx.x;
    if (blk < 500) {
        const int n = threadIdx.x & 127;
        const int j = blk * 2 + (threadIdx.x >> 7);
        if (j >= nrel) return;
        float a = 0.f;
        for (int k = 0; k < EMB; ++k)
            a = fmaf(rel[(size_t)j * EMB + k], Dr[(size_t)k * EMB + n], a);
        Rp[(size_t)j * EMB + n] = a;
    } else {
        const int idx  = (blk - 500) * 256 + threadIdx.x;   // 0..16383
        const int e    = idx & 7;
        const int lane = (idx >> 3) & 63;
        const int frag = idx >> 9;
        const int ci = frag & 7, kk = frag >> 3;
        const int k = kk * 32 + (lane >> 4) * 8 + e;
        const int n = ci * 16 + (lane & 15);
        Bimg[idx] = f2bf(De[(size_t)k * EMB + n]);
    }
}

// ---- main kernel: slim registers (<=64 VGPR) -> 8 waves/SIMD, 32 waves/CU ----
// wave w: batch rows (w>>1)*16 .. +15, De-cols (w&1)*64 .. +63
__global__ __launch_bounds__(THREADS, 8)
void projE_main(const int* __restrict__ triple,
                const float* __restrict__ ent,
                const float* __restrict__ bc,
                const float* __restrict__ Rp,
                const u16* __restrict__ Bimg,
                float* __restrict__ out)
{
    __shared__ float part[4][16];   // 256B: col-half partial dots

    const int tid  = threadIdx.x;
    const int lane = tid & 63;
    const int w    = tid >> 6;      // 0..3
    const int l15  = lane & 15;
    const int l4   = lane >> 4;
    const int ch   = w & 1;         // column half
    const int bm0  = blockIdx.x * BM;
    const int g    = bm0 + (w >> 1) * 16 + l15;   // this lane's batch row

    const int hidx = triple[g * 3 + 0];
    const int ridx = triple[g * 3 + 1];
    const int tidx = triple[g * 3 + 2];
    const float* hp = ent + (size_t)hidx * EMB;

    f32x4 acc[4];
    #pragma unroll
    for (int ci = 0; ci < 4; ++ci) acc[ci] = (f32x4){0.f, 0.f, 0.f, 0.f};

    // ---- K loop: load h slice -> convert -> 4 MFMAs -> discard ----
    #pragma unroll
    for (int kk = 0; kk < 4; ++kk) {
        const float4 a0 = *reinterpret_cast<const float4*>(hp + kk * 32 + 8 * l4);
        const float4 a1 = *reinterpret_cast<const float4*>(hp + kk * 32 + 8 * l4 + 4);
        bf16x8 hfrag;
        hfrag[0] = (short)f2bf(a0.x); hfrag[1] = (short)f2bf(a0.y);
        hfrag[2] = (short)f2bf(a0.z); hfrag[3] = (short)f2bf(a0.w);
        hfrag[4] = (short)f2bf(a1.x); hfrag[5] = (short)f2bf(a1.y);
        hfrag[6] = (short)f2bf(a1.z); hfrag[7] = (short)f2bf(a1.w);
        #pragma unroll
        for (int ci = 0; ci < 4; ++ci) {
            const bf16x8 d = *reinterpret_cast<const bf16x8*>(
                Bimg + (((kk * 8 + ch * 4 + ci) << 6) | lane) * 8);   // L2-hot, coalesced
            acc[ci] = __builtin_amdgcn_mfma_f32_16x16x32_bf16(d, hfrag, acc[ci], 0, 0, 0);
        }
    }

    // ---- epilogue: f = tanh(acc + Rp + bc); partial dot over this col-half ----
    const float* rp = Rp  + (size_t)ridx * EMB + ch * 64;
    const float* bp = bc  + (size_t)g    * EMB + ch * 64;
    const float* tp = ent + (size_t)tidx * EMB + ch * 64;

    float dot = 0.f;
    #pragma unroll
    for (int ci = 0; ci < 4; ++ci) {
        const int col = ci * 16 + 4 * l4;
        const float4 r4 = *reinterpret_cast<const float4*>(rp + col);
        const float4 b4 = *reinterpret_cast<const float4*>(bp + col);
        const float4 t4 = *reinterpret_cast<const float4*>(tp + col);
        #pragma unroll
        for (int e = 0; e < 4; ++e) {
            const float x  = acc[ci][e] + (&r4.x)[e] + (&b4.x)[e];
            const float e2 = __expf(2.f * x);
            const float fv = 1.f - __fdividef(2.f, e2 + 1.f);   // tanh(x), inf-safe
            dot = fmaf(fv, (&t4.x)[e], dot);
        }
    }
    dot += __shfl_xor(dot, 16);     // reduce over l4 groups
    dot += __shfl_xor(dot, 32);
    if (lane < 16) part[w][l15] = dot;
    __syncthreads();
    if (ch == 0 && lane < 16) {
        const float tot = part[w][l15] + part[w + 1][l15];
        out[g] = __fdividef(1.f, 1.f + __expf(-tot));
    }
}

extern "C" void kernel_launch(void* const* d_in, const int* in_sizes, int n_in,
                              void* d_out, int out_size, void* d_ws, size_t ws_size,
                              hipStream_t stream) {
    const int*   triple = (const int*)  d_in[0];
    const float* ent    = (const float*)d_in[1];
    const float* rel    = (const float*)d_in[2];
    const float* De     = (const float*)d_in[3];
    const float* Dr     = (const float*)d_in[4];
    const float* bc     = (const float*)d_in[5];
    float* out = (float*)d_out;

    const int batch = in_sizes[0] / 3;          // 131072
    const int nrel  = in_sizes[2] / EMB;        // 1000

    float* Rp = (float*)d_ws;                           // 512000 B
    u16* Bimg = (u16*)((char*)d_ws + 524288);           // 32 KB

    setup_kernel<<<dim3(564), dim3(256), 0, stream>>>(rel, Dr, De, Rp, Bimg, nrel);
    projE_main<<<dim3(batch / BM), dim3(THREADS), 0, stream>>>(triple, ent, bc, Rp, Bimg, out);
}

// Round 8
// 46.056 us; speedup vs baseline: 1.7608x; 1.3282x over previous
//
#include <hip/hip_runtime.h>

#define EMB 128
#define BM 128
#define THREADS 512

typedef __attribute__((ext_vector_type(8))) short bf16x8;   // 8 bf16 (4 VGPRs)
typedef __attribute__((ext_vector_type(4))) float f32x4;
typedef unsigned short u16;

__device__ __forceinline__ u16 f2bf(float f) {
    unsigned u = __builtin_bit_cast(unsigned, f);
    u += 0x7fffu + ((u >> 16) & 1u);           // round-to-nearest-even
    return (u16)(u >> 16);
}

// ---- merged pre-kernel ----
// blocks [0,500): Rp[j][n] = sum_k rel[j][k] * Dr[k][n]   (2 rows j per block)
// blocks [500,564): frag-major bf16 image of De:
//   Bimg[((kk*8+ci)*64 + lane)*8 + e] = bf16( De[kk*32+(lane>>4)*8+e][ci*16+(lane&15)] )
__global__ void setup_kernel(const float* __restrict__ rel,
                             const float* __restrict__ Dr,
                             const float* __restrict__ De,
                             float* __restrict__ Rp,
                             u16* __restrict__ Bimg, int nrel) {
    const int blk = blockIdx.x;
    if (blk < 500) {
        const int n = threadIdx.x & 127;
        const int j = blk * 2 + (threadIdx.x >> 7);
        if (j >= nrel) return;
        float a = 0.f;
        for (int k = 0; k < EMB; ++k)
            a = fmaf(rel[(size_t)j * EMB + k], Dr[(size_t)k * EMB + n], a);
        Rp[(size_t)j * EMB + n] = a;
    } else {
        const int idx  = (blk - 500) * 256 + threadIdx.x;   // 0..16383
        const int e    = idx & 7;
        const int lane = (idx >> 3) & 63;
        const int frag = idx >> 9;
        const int ci = frag & 7, kk = frag >> 3;
        const int k = kk * 32 + (lane >> 4) * 8 + e;
        const int n = ci * 16 + (lane & 15);
        Bimg[idx] = f2bf(De[(size_t)k * EMB + n]);
    }
}

// ---- main kernel: slim (<=64 VGPR) -> 8 waves/EU, 4 blocks/CU, 32 waves/CU ----
// wave w: batch rows w*16..w*16+15, ALL 128 cols (no traffic duplication)
__global__ __launch_bounds__(THREADS, 8)
void projE_main(const int* __restrict__ triple,
                const float* __restrict__ ent,
                const float* __restrict__ bc,
                const float* __restrict__ Rp,
                const u16* __restrict__ Bimg,
                float* __restrict__ out)
{
    __shared__ u16 Bs[16384];       // 32KB, frag-major De image (conflict-free reads)

    const int tid  = threadIdx.x;
    const int lane = tid & 63;
    const int w    = tid >> 6;      // wave 0..7
    const int l15  = lane & 15;
    const int l4   = lane >> 4;
    const int bm0  = blockIdx.x * BM;

    // ---- stage De image: 32KB linear copy, global -> LDS direct ----
    {
        const __attribute__((address_space(1))) char* gB =
            (const __attribute__((address_space(1))) char*)Bimg;
        __attribute__((address_space(3))) char* lB =
            (__attribute__((address_space(3))) char*)Bs;
        #pragma unroll
        for (int i = 0; i < 4; ++i) {
            const int off = (i * THREADS + tid) * 16;   // wave-uniform base + lane*16
            __builtin_amdgcn_global_load_lds(
                (const __attribute__((address_space(1))) void*)(gB + off),
                (__attribute__((address_space(3))) void*)(lB + off), 16, 0, 0);
        }
    }

    const int g    = bm0 + w * 16 + l15;      // this lane's batch row
    const int hidx = triple[g * 3 + 0];
    const float* hp = ent + (size_t)hidx * EMB;

    f32x4 acc[8];
    #pragma unroll
    for (int ci = 0; ci < 8; ++ci) acc[ci] = (f32x4){0.f, 0.f, 0.f, 0.f};

    __syncthreads();   // B visible to all waves

    // ---- K loop: load h slice -> convert -> 8 MFMAs -> discard (low live state) ----
    #pragma unroll
    for (int kk = 0; kk < 4; ++kk) {
        const float4 a0 = *reinterpret_cast<const float4*>(hp + kk * 32 + 8 * l4);
        const float4 a1 = *reinterpret_cast<const float4*>(hp + kk * 32 + 8 * l4 + 4);
        bf16x8 hfrag;
        hfrag[0] = (short)f2bf(a0.x); hfrag[1] = (short)f2bf(a0.y);
        hfrag[2] = (short)f2bf(a0.z); hfrag[3] = (short)f2bf(a0.w);
        hfrag[4] = (short)f2bf(a1.x); hfrag[5] = (short)f2bf(a1.y);
        hfrag[6] = (short)f2bf(a1.z); hfrag[7] = (short)f2bf(a1.w);
        #pragma unroll
        for (int ci = 0; ci < 8; ++ci) {
            const bf16x8 d = *reinterpret_cast<const bf16x8*>(&Bs[((kk * 8 + ci) << 6 | lane) * 8]);
            acc[ci] = __builtin_amdgcn_mfma_f32_16x16x32_bf16(d, hfrag, acc[ci], 0, 0, 0);
        }
    }

    // ---- epilogue: f = tanh(acc + Rp[ridx] + bc); out = sigmoid(f . t) ----
    const int ridx = triple[g * 3 + 1];
    const int tidx = triple[g * 3 + 2];
    const float* rp = Rp  + (size_t)ridx * EMB;
    const float* bp = bc  + (size_t)g    * EMB;
    const float* tp = ent + (size_t)tidx * EMB;

    float dot = 0.f;
    #pragma unroll
    for (int ci = 0; ci < 8; ++ci) {
        const int col = ci * 16 + 4 * l4;      // 4 consecutive cols per lane
        const float4 r4 = *reinterpret_cast<const float4*>(rp + col);
        const float4 b4 = *reinterpret_cast<const float4*>(bp + col);
        const float4 t4 = *reinterpret_cast<const float4*>(tp + col);
        #pragma unroll
        for (int e = 0; e < 4; ++e) {
            const float x  = acc[ci][e] + (&r4.x)[e] + (&b4.x)[e];
            const float e2 = __expf(2.f * x);
            const float fv = 1.f - __fdividef(2.f, e2 + 1.f);   // tanh(x), inf-safe
            dot = fmaf(fv, (&t4.x)[e], dot);
        }
    }
    dot += __shfl_xor(dot, 16);
    dot += __shfl_xor(dot, 32);
    if (lane < 16) out[g] = __fdividef(1.f, 1.f + __expf(-dot));
}

extern "C" void kernel_launch(void* const* d_in, const int* in_sizes, int n_in,
                              void* d_out, int out_size, void* d_ws, size_t ws_size,
                              hipStream_t stream) {
    const int*   triple = (const int*)  d_in[0];
    const float* ent    = (const float*)d_in[1];
    const float* rel    = (const float*)d_in[2];
    const float* De     = (const float*)d_in[3];
    const float* Dr     = (const float*)d_in[4];
    const float* bc     = (const float*)d_in[5];
    float* out = (float*)d_out;

    const int batch = in_sizes[0] / 3;          // 131072
    const int nrel  = in_sizes[2] / EMB;        // 1000

    float* Rp = (float*)d_ws;                           // 512000 B
    u16* Bimg = (u16*)((char*)d_ws + 524288);           // 32 KB

    setup_kernel<<<dim3(564), dim3(256), 0, stream>>>(rel, Dr, De, Rp, Bimg, nrel);
    projE_main<<<dim3(batch / BM), dim3(THREADS), 0, stream>>>(triple, ent, bc, Rp, Bimg, out);
}